// Round 5
// baseline (145.644 us; speedup 1.0000x reference)
//
#include <hip/hip_runtime.h>
#include <hip/hip_bf16.h>
#include <cstddef>

#define NH 16
#define NKV 4
#define HD 128
#define SEQ 1024
#define SCALE_F 0.08838834764831845f
#define LOG2E 1.44269504088896f

typedef __attribute__((ext_vector_type(8))) short short8;
typedef __attribute__((ext_vector_type(4))) short bshort4;
typedef __attribute__((ext_vector_type(4))) float floatx4;

union F8 { short8 v; bshort4 h[2]; unsigned short u[8]; };
union PK { bshort4 v; unsigned int u[2]; };

__device__ __forceinline__ unsigned short f2bf(float f) {
  unsigned int u = __float_as_uint(f);
  u += 0x7FFFu + ((u >> 16) & 1u);
  return (unsigned short)(u >> 16);
}

__device__ __forceinline__ unsigned int pkbf(float a, float b) {
  union { __hip_bfloat162 h; unsigned int u; } c;
  c.h = __float22bfloat162_rn(float2{a, b});  // a -> low 16, b -> high 16
  return c.u;
}

__device__ __forceinline__ void glds16(const void* g, void* l) {
  __builtin_amdgcn_global_load_lds(
      (const __attribute__((address_space(1))) unsigned int*)g,
      (__attribute__((address_space(3))) unsigned int*)l, 16, 0, 0);
}

// ---------------------------------------------------------------------------
// Pre-pass.
// K -> bf16 tiled+swizzled [512 tiles][32 kpos][16 blk], blk = kpos*16 +
//   (d8 ^ (kpos&15)); one b128 read at (col*16+((ks*4+quad)^col)) gives the
//   16x16x32 A-fragment (m=kpos, k=d).  [R3-proven layout]
// V -> bf16 "x16-A-frag" layout: per tile, slot s = dt*64 + col*4 +
//   (quad ^ (col&3)); slot content u[mt*4+j] = V[kpos=mt*16+quad*4+j][d=
//   dt*16+col].  One b128 read gives BOTH K=16 halves of the PV A-fragment
//   (m=d_local, k=kpos).
// ---------------------------------------------------------------------------
__global__ __launch_bounds__(256) void prepass(const float* __restrict__ kg,
                                               const float* __restrict__ vg,
                                               unsigned short* __restrict__ Ktg,
                                               unsigned short* __restrict__ Vtg) {
  __shared__ float Vl[32 * 132];
  const int tid = threadIdx.x;
  const int bid = blockIdx.x;
  if (bid < 512) {
    const int bkvh = bid >> 5, tile = bid & 31;
    const int b = bkvh >> 2, kvh = bkvh & 3;
    const int kpos = tid >> 3;
    const int d8base = (tid & 7) * 2;
    const size_t tok = (size_t)b * SEQ + tile * 32 + kpos;
    const float* src = kg + (tok * NKV + kvh) * HD + d8base * 8;
    unsigned short* dstT = Ktg + (size_t)bid * 4096;
#pragma unroll
    for (int i = 0; i < 2; ++i) {
      floatx4 a = ((const floatx4*)src)[0];
      floatx4 c = ((const floatx4*)src)[1];
      F8 t;
#pragma unroll
      for (int j = 0; j < 4; ++j) { t.u[j] = f2bf(a[j]); t.u[4 + j] = f2bf(c[j]); }
      const int blk = kpos * 16 + ((d8base + i) ^ (kpos & 15));
      *(short8*)(dstT + blk * 8) = t.v;
      src += 8;
    }
  } else {
    const int bb = bid - 512;
    const int bkvh = bb >> 5, tile = bb & 31;
    const int b = bkvh >> 2, kvh = bkvh & 3;
    const int r = tid >> 3;
    const int c16 = (tid & 7) * 16;
    const size_t tok = (size_t)b * SEQ + tile * 32 + r;
    const float* src = vg + (tok * NKV + kvh) * HD + c16;
#pragma unroll
    for (int j = 0; j < 4; ++j)
      *(floatx4*)&Vl[r * 132 + c16 + j * 4] = ((const floatx4*)src)[j];
    __syncthreads();
    unsigned short* dstT = Vtg + (size_t)bb * 4096;
#pragma unroll
    for (int i = 0; i < 2; ++i) {
      const int s = tid * 2 + i;          // storage slot 0..511
      const int dt = s >> 6;
      const int rem = s & 63;
      const int col = rem >> 2;           // d_local = dt*16+col
      const int qpos = rem & 3;
      const int quad = qpos ^ (col & 3);  // reader's quad (self-inverse swizzle)
      F8 t;
#pragma unroll
      for (int mt = 0; mt < 2; ++mt)
#pragma unroll
        for (int j = 0; j < 4; ++j)
          t.u[mt * 4 + j] = f2bf(Vl[(mt * 16 + quad * 4 + j) * 132 + dt * 16 + col]);
      *(short8*)(dstT + s * 8) = t.v;
    }
  }
}

// ---------------------------------------------------------------------------
// Hot kernel: grid 1024 x 128 threads (2 waves), 64 q-rows/block, 32/wave.
// S^T scheme: QK as mfma(A=K, B=Q) -> S^T; exp in-place; PV as
// mfma_16x16x16(A=V^T frag, B=P^T from regs) -> O^T.  No P LDS round-trip.
// Double-buffered DMA staging; max-free softmax with exp2 (log2e folded
// into Q scale); one barrier per k-tile.
// ---------------------------------------------------------------------------
__global__ __launch_bounds__(128, 2)
void fa_fwd3(const float* __restrict__ qg, const unsigned short* __restrict__ Ktg,
             const unsigned short* __restrict__ Vtg, float* __restrict__ og) {
  __shared__ __align__(16) unsigned short Kb[2][4096];
  __shared__ __align__(16) unsigned short Vb[2][4096];

  const int tid = threadIdx.x;
  const int wave = tid >> 6;
  const int lane = tid & 63;
  const int col = lane & 15;
  const int quad = lane >> 4;

  const int idx = blockIdx.x;
  // Co-resident {i,i+256,i+512,i+768}: qt = g*4+((u+g)&3), per-CU qt sum = 30
  // for every u -> uniform 68 k-tiles/CU under round-robin or XCD(%8) models.
  const int g = idx >> 8;
  const int u = (idx >> 6) & 3;
  const int bh = idx & 63;
  const int qt = g * 4 + ((u + g) & 3);  // 0..15 (64-row q tiles)
  const int h = bh & 15;
  const int b = bh >> 4;
  const int kvh = h >> 2;
  const int seg = b * SEQ;
  const int wq0 = qt * 64 + wave * 32;   // wave's first q row
  const int tb = (b * NKV + kvh) * 32;   // tile index base

  // Q B-fragments [n=q=lane&15][k=quad*8+j], scaled by SCALE*log2e, bf16.
  F8 qf[2][4];
#pragma unroll
  for (int nt = 0; nt < 2; ++nt) {
    const float* qp =
        qg + ((size_t)(seg + wq0 + nt * 16 + col) * NH + h) * HD + quad * 8;
#pragma unroll
    for (int ks = 0; ks < 4; ++ks) {
      floatx4 a = ((const floatx4*)(qp + ks * 32))[0];
      floatx4 c = ((const floatx4*)(qp + ks * 32))[1];
#pragma unroll
      for (int j = 0; j < 4; ++j) {
        qf[nt][ks].u[j] = f2bf(a[j] * (SCALE_F * LOG2E));
        qf[nt][ks].u[4 + j] = f2bf(c[j] * (SCALE_F * LOG2E));
      }
    }
  }

  floatx4 acc[2][8];  // O^T: [nt][dt], C-layout col=q, row=d_local
#pragma unroll
  for (int nt = 0; nt < 2; ++nt)
#pragma unroll
    for (int dt = 0; dt < 8; ++dt) acc[nt][dt] = (floatx4){0.f, 0.f, 0.f, 0.f};
  float lsum[2] = {0.f, 0.f};  // per-lane partial row sum, q = col

  const int nkt = 2 * (qt + 1);
  const int stg = wave * 4096 + lane * 16;  // global staging offset (bytes)
  const int stl = wave * 4096;              // wave-uniform LDS base offset

  // Prologue: DMA tile 0 into buffer 0 (each wave stages 4KB of K + 4KB of V)
  {
    const char* gK = (const char*)Ktg + (size_t)tb * 8192 + stg;
    const char* gV = (const char*)Vtg + (size_t)tb * 8192 + stg;
    char* lK = (char*)&Kb[0][0] + stl;
    char* lV = (char*)&Vb[0][0] + stl;
#pragma unroll
    for (int o = 0; o < 4096; o += 1024) {
      glds16(gK + o, lK + o);
      glds16(gV + o, lV + o);
    }
  }
  __syncthreads();

  for (int kt = 0; kt < nkt; ++kt) {
    const int cb = kt & 1, nb = cb ^ 1;
    if (kt + 1 < nkt) {  // prefetch next tile; drained by this iter's barrier
      const char* gK = (const char*)Ktg + (size_t)(tb + kt + 1) * 8192 + stg;
      const char* gV = (const char*)Vtg + (size_t)(tb + kt + 1) * 8192 + stg;
      char* lK = (char*)&Kb[nb][0] + stl;
      char* lV = (char*)&Vb[nb][0] + stl;
#pragma unroll
      for (int o = 0; o < 4096; o += 1024) {
        glds16(gK + o, lK + o);
        glds16(gV + o, lV + o);
      }
    }
    const int kbase = kt * 32;
    if (kbase <= wq0 + 31) {
      // ---- QK^T -> S^T: A = K frag (m=kpos), B = Q frag (n=q) ----
      floatx4 st[2][2];  // [nt][mt]
#pragma unroll
      for (int nt = 0; nt < 2; ++nt)
#pragma unroll
        for (int mt = 0; mt < 2; ++mt) st[nt][mt] = (floatx4){0.f, 0.f, 0.f, 0.f};
#pragma unroll
      for (int mt = 0; mt < 2; ++mt)
#pragma unroll
        for (int ks = 0; ks < 4; ++ks) {
          F8 kf;
          kf.v = *(const short8*)&Kb[cb][((mt * 16 + col) * 16 +
                                          ((ks * 4 + quad) ^ col)) * 8];
          st[0][mt] = __builtin_amdgcn_mfma_f32_16x16x32_bf16(
              kf.v, qf[0][ks].v, st[0][mt], 0, 0, 0);
          st[1][mt] = __builtin_amdgcn_mfma_f32_16x16x32_bf16(
              kf.v, qf[1][ks].v, st[1][mt], 0, 0, 0);
        }
      // ---- softmax (max-free, exp2) + pack P^T to B-frags in regs ----
      const bool diag = (kbase + 31 > wq0);
      PK pf[2][2];  // [nt][mt] -> 16x16x16 B-fragment (k=quad*4+j, n=q)
#pragma unroll
      for (int nt = 0; nt < 2; ++nt) {
#pragma unroll
        for (int mt = 0; mt < 2; ++mt) {
          float p[4];
#pragma unroll
          for (int r = 0; r < 4; ++r) {
            p[r] = exp2f(st[nt][mt][r]);
            if (diag) {
              const int kpos_g = kbase + mt * 16 + quad * 4 + r;
              if (kpos_g > wq0 + nt * 16 + col) p[r] = 0.f;
            }
          }
          lsum[nt] += (p[0] + p[1]) + (p[2] + p[3]);
          pf[nt][mt].u[0] = pkbf(p[0], p[1]);
          pf[nt][mt].u[1] = pkbf(p[2], p[3]);
        }
      }
      // ---- PV: A = V^T frag (one b128 = both K=16 halves), B = P^T ----
#pragma unroll
      for (int dt = 0; dt < 8; ++dt) {
        F8 vf;
        vf.v = *(const short8*)&Vb[cb][(dt * 64 + col * 4 +
                                        (quad ^ (col & 3))) * 8];
#pragma unroll
        for (int nt = 0; nt < 2; ++nt) {
          acc[nt][dt] = __builtin_amdgcn_mfma_f32_16x16x16bf16_1k(
              vf.h[0], pf[nt][0].v, acc[nt][dt], 0, 0, 0);
          acc[nt][dt] = __builtin_amdgcn_mfma_f32_16x16x16bf16_1k(
              vf.h[1], pf[nt][1].v, acc[nt][dt], 0, 0, 0);
        }
      }
    }
    __syncthreads();
  }

  // ---- epilogue: reduce lsum across quads, normalize, store O (dwordx4) ----
#pragma unroll
  for (int nt = 0; nt < 2; ++nt) {
    float l = lsum[nt];
    l += __shfl_xor(l, 16);
    l += __shfl_xor(l, 32);
    const float inv = 1.0f / l;
    float* op = og + ((size_t)(seg + wq0 + nt * 16 + col) * NH + h) * HD +
                quad * 4;
#pragma unroll
    for (int dt = 0; dt < 8; ++dt) {
      floatx4 o = acc[nt][dt];
      o[0] *= inv; o[1] *= inv; o[2] *= inv; o[3] *= inv;
      *(floatx4*)(op + dt * 16) = o;
    }
  }
}

// ---------------------------------------------------------------------------
// Fallback (R2 kernel) if d_ws is too small for the pre-pass buffers.
// ---------------------------------------------------------------------------
#define KST 136
#define VST 40
#define PST 40

__global__ __launch_bounds__(256, 2)
void fa_fwd(const float* __restrict__ qg, const float* __restrict__ kg,
            const float* __restrict__ vg, float* __restrict__ og) {
  __shared__ unsigned short Klds[32 * KST];
  __shared__ unsigned short Vt[HD * VST];
  __shared__ unsigned short Pl[4][32 * PST];

  const int tid = threadIdx.x;
  const int wave = tid >> 6;
  const int lane = tid & 63;
  const int col = lane & 15;
  const int quad = lane >> 4;

  const int idx = blockIdx.x;
  const int raw = idx & 7;
  const int qt = (idx & 256) ? raw : 7 - raw;
  const int bh = idx >> 3;
  const int h = bh & 15;
  const int b = bh >> 4;
  const int kvh = h >> 2;
  const int seg = b * SEQ;
  const int wq0 = qt * 128 + wave * 32;

  F8 qf[2][4];
#pragma unroll
  for (int mt = 0; mt < 2; ++mt) {
    const size_t qrow = (size_t)(seg + wq0 + mt * 16 + col);
    const float* qp = qg + (qrow * NH + h) * HD + quad * 8;
#pragma unroll
    for (int ks = 0; ks < 4; ++ks) {
      const floatx4* p4 = (const floatx4*)(qp + ks * 32);
      floatx4 a = p4[0], c = p4[1];
#pragma unroll
      for (int j = 0; j < 4; ++j) {
        qf[mt][ks].u[j] = f2bf(a[j] * SCALE_F);
        qf[mt][ks].u[4 + j] = f2bf(c[j] * SCALE_F);
      }
    }
  }

  floatx4 acc[2][8];
#pragma unroll
  for (int mt = 0; mt < 2; ++mt)
#pragma unroll
    for (int dt = 0; dt < 8; ++dt)
      acc[mt][dt] = (floatx4){0.f, 0.f, 0.f, 0.f};
  float lsum[2][4];
#pragma unroll
  for (int mt = 0; mt < 2; ++mt)
#pragma unroll
    for (int r = 0; r < 4; ++r) lsum[mt][r] = 0.f;

  const int nkt = 4 * (qt + 1);
  const int sr = tid >> 3;
  const int sc = (tid & 7) * 16;

  for (int kt = 0; kt < nkt; ++kt) {
    const int kbase = kt * 32;
    __syncthreads();
    {
      const size_t tok = (size_t)(seg + kbase + sr);
      const floatx4* kp4 = (const floatx4*)(kg + (tok * NKV + kvh) * HD + sc);
      floatx4 kv0 = kp4[0], kv1 = kp4[1], kv2 = kp4[2], kv3 = kp4[3];
      float kf32[16] = {kv0[0],kv0[1],kv0[2],kv0[3], kv1[0],kv1[1],kv1[2],kv1[3],
                        kv2[0],kv2[1],kv2[2],kv2[3], kv3[0],kv3[1],kv3[2],kv3[3]};
      unsigned int* dst = (unsigned int*)&Klds[sr * KST + sc];
#pragma unroll
      for (int j = 0; j < 8; ++j)
        dst[j] = (unsigned int)f2bf(kf32[2 * j]) | ((unsigned int)f2bf(kf32[2 * j + 1]) << 16);
      const floatx4* vp4 = (const floatx4*)(vg + (tok * NKV + kvh) * HD + sc);
      floatx4 vv0 = vp4[0], vv1 = vp4[1], vv2 = vp4[2], vv3 = vp4[3];
      unsigned short vb[16] = {
        f2bf(vv0[0]),f2bf(vv0[1]),f2bf(vv0[2]),f2bf(vv0[3]),
        f2bf(vv1[0]),f2bf(vv1[1]),f2bf(vv1[2]),f2bf(vv1[3]),
        f2bf(vv2[0]),f2bf(vv2[1]),f2bf(vv2[2]),f2bf(vv2[3]),
        f2bf(vv3[0]),f2bf(vv3[1]),f2bf(vv3[2]),f2bf(vv3[3])};
#pragma unroll
      for (int s = 0; s < 16; ++s) {
        int j = (s + tid) & 15;
        Vt[(sc + j) * VST + sr] = vb[j];
      }
    }
    __syncthreads();

    if (kbase > wq0 + 31) continue;

    F8 kf[4][2];
#pragma unroll
    for (int ks = 0; ks < 4; ++ks)
#pragma unroll
      for (int nt = 0; nt < 2; ++nt)
        kf[ks][nt].v = *(const short8*)&Klds[(nt * 16 + col) * KST + ks * 32 + quad * 8];

#pragma unroll
    for (int mt = 0; mt < 2; ++mt) {
      floatx4 s0 = {0.f, 0.f, 0.f, 0.f}, s1 = {0.f, 0.f, 0.f, 0.f};
#pragma unroll
      for (int ks = 0; ks < 4; ++ks) {
        s0 = __builtin_amdgcn_mfma_f32_16x16x32_bf16(qf[mt][ks].v, kf[ks][0].v, s0, 0, 0, 0);
        s1 = __builtin_amdgcn_mfma_f32_16x16x32_bf16(qf[mt][ks].v, kf[ks][1].v, s1, 0, 0, 0);
      }
      const int q0 = wq0 + mt * 16 + quad * 4;
      const bool diag = (kbase + 31 > wq0 + mt * 16);
      unsigned short* pw = &Pl[wave][(mt * 16 + quad * 4) * PST];
#pragma unroll
      for (int r = 0; r < 4; ++r) {
        float p0 = __expf(s0[r]);
        float p1 = __expf(s1[r]);
        if (diag) {
          p0 = (kbase + col > q0 + r) ? 0.f : p0;
          p1 = (kbase + 16 + col > q0 + r) ? 0.f : p1;
        }
        lsum[mt][r] += p0 + p1;
        pw[r * PST + col] = f2bf(p0);
        pw[r * PST + 16 + col] = f2bf(p1);
      }
    }
    F8 pa[2];
#pragma unroll
    for (int mt = 0; mt < 2; ++mt)
      pa[mt].v = *(const short8*)&Pl[wave][(mt * 16 + col) * PST + quad * 8];
#pragma unroll
    for (int dt = 0; dt < 8; ++dt) {
      F8 vb;
      vb.v = *(const short8*)&Vt[(dt * 16 + col) * VST + quad * 8];
#pragma unroll
      for (int mt = 0; mt < 2; ++mt)
        acc[mt][dt] = __builtin_amdgcn_mfma_f32_16x16x32_bf16(pa[mt].v, vb.v, acc[mt][dt], 0, 0, 0);
    }
  }

#pragma unroll
  for (int mt = 0; mt < 2; ++mt) {
#pragma unroll
    for (int r = 0; r < 4; ++r) {
      float l = lsum[mt][r];
      l += __shfl_xor(l, 1);
      l += __shfl_xor(l, 2);
      l += __shfl_xor(l, 4);
      l += __shfl_xor(l, 8);
      const float inv = 1.0f / l;
      const int qi = wq0 + mt * 16 + quad * 4 + r;
      float* op = og + ((size_t)(seg + qi) * NH + h) * HD;
#pragma unroll
      for (int dt = 0; dt < 8; ++dt)
        op[dt * 16 + col] = acc[mt][dt][r] * inv;
    }
  }
}

extern "C" void kernel_launch(void* const* d_in, const int* in_sizes, int n_in,
                              void* d_out, int out_size, void* d_ws, size_t ws_size,
                              hipStream_t stream) {
  const float* q = (const float*)d_in[0];
  const float* k = (const float*)d_in[1];
  const float* v = (const float*)d_in[2];
  float* out = (float*)d_out;
  if (ws_size >= (size_t)(8 * 1024 * 1024)) {
    unsigned short* Ktg = (unsigned short*)d_ws;
    unsigned short* Vtg = Ktg + 2097152;  // +4MB
    hipLaunchKernelGGL(prepass, dim3(1024), dim3(256), 0, stream, k, v, Ktg, Vtg);
    hipLaunchKernelGGL(fa_fwd3, dim3(1024), dim3(128), 0, stream, q, Ktg, Vtg, out);
  } else {
    hipLaunchKernelGGL(fa_fwd, dim3(512), dim3(256), 0, stream, q, k, v, out);
  }
}